// Round 5
// baseline (493.036 us; speedup 1.0000x reference)
//
#include <hip/hip_runtime.h>
#include <cstdint>
#include <cstddef>

typedef _Float16 half8 __attribute__((ext_vector_type(8)));
typedef _Float16 half4 __attribute__((ext_vector_type(4)));
typedef float f32x4 __attribute__((ext_vector_type(4)));

// async global->LDS, 16B per lane; LDS dest must be wave-uniform base + lane*16
#define GLDS16(g, l) __builtin_amdgcn_global_load_lds( \
    (__attribute__((address_space(1))) void*)(g), \
    (__attribute__((address_space(3))) void*)(l), 16, 0, 0)

// raw barrier preceded by LDS-drain only (global stores stay in flight)
#define LBAR() do { asm volatile("s_waitcnt lgkmcnt(0)" ::: "memory"); \
                    __builtin_amdgcn_s_barrier(); } while (0)

// ---------------------------------------------------------------------------
// fp32 -> fp16 convert
// ---------------------------------------------------------------------------
__global__ __launch_bounds__(256) void cvt_f32_f16(const float* __restrict__ src,
                                                   _Float16* __restrict__ dst, int n) {
  int i = (blockIdx.x * 256 + threadIdx.x) * 8;
  if (i >= n) return;
  float4 a = *(const float4*)(src + i);
  float4 b = *(const float4*)(src + i + 4);
  half8 h;
  h[0] = (_Float16)a.x; h[1] = (_Float16)a.y; h[2] = (_Float16)a.z; h[3] = (_Float16)a.w;
  h[4] = (_Float16)b.x; h[5] = (_Float16)b.y; h[6] = (_Float16)b.z; h[7] = (_Float16)b.w;
  *(half8*)(dst + i) = h;
}

// ---------------------------------------------------------------------------
// GEMM C[m,n] = sum_k A[m,k]*Bw[n,k] (+bias).  A fp16 MxK, Bw fp16 NxK, K=512.
// 256x128 tile, BK=32, 4 waves (2Mx2N) of 128x64 wave tiles (8x4 MFMAs).
// Design point: good wave-tile intensity (128x64) x INDEPENDENT-block
// concurrency. 72 KB LDS + ~220 regs -> 2 blocks/CU, each 1 wave/SIMD with
// its own barriers: block B's MFMAs fill block A's barrier/waitcnt holes
// (m114 co-schedule). Lockstep 8-wave 256^2 variants were pinned at 153 us
// across 3 schedules; this is the unexplored axis.
//
// LDS in MFMA FRAGMENT ORDER: band (16 rows) x 4 chunks of 8 halves; slot
// (r,c) = c*16+r, so glds writes and ds_read_b128 are both base + lane*16.
//
// Pipeline (R1-proven ledger, depth-2): 3 buffers; iter k top:
//   vmcnt(6)  [tile k landed; tile k+1's 6 loads stay in flight]
//   barrier; stage(k+2)->buf[(k+2)%3] (last read iter k-1, 2 barriers ago)
//   ds_read buf[k%3]; setprio(1) 32 MFMA setprio(0); barrier
// ---------------------------------------------------------------------------
template<int NOUT, int NT, bool BIAS>
__global__ __launch_bounds__(256, 2) void gemm_wide(const _Float16* __restrict__ A,
                                                    const _Float16* __restrict__ Bw,
                                                    const float* __restrict__ bias,
                                                    void* __restrict__ Cout) {
  constexpr int K = 512;
  constexpr int NIT = K / 32;      // 16 K-steps
  __shared__ union {
    _Float16 S[3][12288];          // [buf][A: 0..8191 | B: 8192..12287]
    float E[2][16][132];           // epilogue staging (R1-proven layout)
  } u;
  const int id  = blockIdx.x;
  const int xcd = id & 7;                 // XCD cohort: N-tiles of a band share L2
  const int jj  = id >> 3;
  const int by  = (jj / NT) * 8 + xcd;
  const int bx  = jj % NT;
  const int m_base = by * 256, n_base = bx * 128;

  const int t    = threadIdx.x;    // 0..255
  const int lane = t & 63;
  const int wid  = t >> 6;         // 0..3
  const int wm   = wid >> 1;       // M half: rows wm*128..+127
  const int wn   = wid & 1;        // N half: cols wn*64..+63
  const int cl   = lane & 15, q = lane >> 4;

  f32x4 acc[8][4] = {};

  // staging slots: slot s -> band=s>>6 (16 rows x 4 chunks), r=((s>>6)<<4)|(s&15),
  // ch=(s>>4)&3.  A tile: 1024 slots (thread t owns t+i*256, i=0..3);
  // B tile: 512 slots (i=0..1).  6 GLDS16 per thread per K-tile.
  const _Float16* aP[4];
  const _Float16* bP[2];
#pragma unroll
  for (int i = 0; i < 4; ++i) {
    const int s = t + i * 256;
    const int r = ((s >> 6) << 4) | (s & 15), ch = (s >> 4) & 3;
    aP[i] = A + (size_t)(m_base + r) * K + ch * 8;
  }
#pragma unroll
  for (int i = 0; i < 2; ++i) {
    const int s = t + i * 256;
    const int r = ((s >> 6) << 4) | (s & 15), ch = (s >> 4) & 3;
    bP[i] = Bw + (size_t)(n_base + r) * K + ch * 8;
  }
  auto stage = [&](int kt) {
    const int p = kt % 3;
    const int ko = kt * 32;
    char* base = (char*)&u.S[p][0];
#pragma unroll
    for (int i = 0; i < 4; ++i)
      GLDS16(aP[i] + ko, base + (t + i * 256) * 16);
#pragma unroll
    for (int i = 0; i < 2; ++i)
      GLDS16(bP[i] + ko, base + 16384 + (t + i * 256) * 16);
  };

  stage(0);
  stage(1);

  const int lane8 = lane * 8;
#pragma unroll
  for (int k = 0; k < NIT; ++k) {
    // tile k ready; tile k+1's 6 loads stay in flight across the barrier
    if (k < NIT - 1) asm volatile("s_waitcnt vmcnt(6)" ::: "memory");
    else             asm volatile("s_waitcnt vmcnt(0)" ::: "memory");
    __builtin_amdgcn_s_barrier();
    asm volatile("" ::: "memory");   // no LDS read hoisted above the barrier
    if (k + 2 < NIT) stage(k + 2);

    const _Float16* As = &u.S[k % 3][0];
    const _Float16* Bs = &u.S[k % 3][8192];
    half8 af[8], bf[4];
#pragma unroll
    for (int fm = 0; fm < 8; ++fm)
      af[fm] = *(const half8*)(As + (wm * 8 + fm) * 512 + lane8);
#pragma unroll
    for (int fn = 0; fn < 4; ++fn)
      bf[fn] = *(const half8*)(Bs + (wn * 4 + fn) * 512 + lane8);
    __builtin_amdgcn_s_setprio(1);
#pragma unroll
    for (int fm = 0; fm < 8; ++fm)
#pragma unroll
      for (int fn = 0; fn < 4; ++fn)
        acc[fm][fn] = __builtin_amdgcn_mfma_f32_16x16x32_f16(af[fm], bf[fn],
                                                             acc[fm][fn], 0, 0, 0);
    __builtin_amdgcn_s_setprio(0);
    __builtin_amdgcn_s_barrier();  // all reads of buf[k%3] done before re-stage
  }
  __syncthreads();   // drain before E overlays S

  // epilogue: round j stages band j of wm=0 (rows m_base+j*16) and of wm=1
  // (rows m_base+128+j*16); acc index j is compile-time under the unroll.
  // E row stride 132 -> read chunk ((ecs-erow)&7)+8*jo keeps bank group == ecs.
  const int eb = t >> 7, erow = (t >> 3) & 15, ecs = t & 7;
#pragma unroll
  for (int j = 0; j < 8; ++j) {
#pragma unroll
    for (int fn = 0; fn < 4; ++fn)
#pragma unroll
      for (int r = 0; r < 4; ++r)
        u.E[wm][q * 4 + r][wn * 64 + fn * 16 + cl] = acc[j][fn][r];
    LBAR();
    const size_t rg = (size_t)(m_base + eb * 128 + j * 16 + erow);
#pragma unroll
    for (int jo = 0; jo < 4; ++jo) {
      const int ch = ((ecs - erow) & 7) + 8 * jo;
      const int cc = ch * 4;
      float4 e = *(const float4*)&u.E[eb][erow][cc];
      if constexpr (BIAS) {
        const float4 bb = *(const float4*)(bias + n_base + cc);
        e.x += bb.x; e.y += bb.y; e.z += bb.z; e.w += bb.w;
        *(float4*)((float*)Cout + rg * NOUT + n_base + cc) = e;
      } else {
        half4 hv;
        hv[0] = (_Float16)e.x; hv[1] = (_Float16)e.y;
        hv[2] = (_Float16)e.z; hv[3] = (_Float16)e.w;
        *(half4*)((_Float16*)Cout + rg * NOUT + n_base + cc) = hv;
      }
    }
    LBAR();
  }
}

// ---------------------------------------------------------------------------
// Windowed attention: one block per (head h, window b). W=64, hd=64.
// Q direct to registers (fragment pattern == what staging loaded anyway);
// K via glds fragment-order; V manual transpose; output staged through Os
// for coalesced 16B stores (R4's scattered direct stores reverted).
// LDS 35.8 KB -> 4 blocks/CU (16 waves).
// ---------------------------------------------------------------------------
__global__ __launch_bounds__(256, 4) void attn_win(const _Float16* __restrict__ QKV,
                                                   _Float16* __restrict__ Out) {
  __shared__ _Float16 Ks[4096];
  __shared__ _Float16 Vt[64][72];   // V transposed: Vt[e][j], padded rows
  __shared__ _Float16 Ps[64][72];   // softmax probs
  __shared__ _Float16 Os[64][72];   // output staging
  const int h = blockIdx.x, b = blockIdx.y;
  const int t = threadIdx.x;
  const int lane = t & 63, wid = t >> 6;
  const int cl = lane & 15, q = lane >> 4;
  const int m0 = wid * 16;          // wave's 16 query rows
  const int lane8 = lane * 8;

  // ---- stage K (async, fragment order) and V (manual transpose) ----
  {
    const int s0 = t, s1 = t + 256;
    const int r0 = ((s0 >> 7) << 4) | (s0 & 15), ch0 = (s0 >> 4) & 7;
    const int r1 = ((s1 >> 7) << 4) | (s1 & 15), ch1 = (s1 >> 4) & 7;
    const _Float16* g0 = QKV + (size_t)(b * 64 + r0) * 1536 + 512 + h * 64 + ch0 * 8;
    const _Float16* g1 = QKV + (size_t)(b * 64 + r1) * 1536 + 512 + h * 64 + ch1 * 8;
    GLDS16(g0, (char*)Ks + s0 * 16);
    GLDS16(g1, (char*)Ks + s1 * 16);

    const int vj = t & 63, vp = t >> 6;   // row j of V, 16-half chunk vp
    const _Float16* vsrc = QKV + (size_t)(b * 64 + vj) * 1536 + 1024 + h * 64 + vp * 16;
    half8 v0 = *(const half8*)vsrc;
    half8 v1 = *(const half8*)(vsrc + 8);
#pragma unroll
    for (int i = 0; i < 8; i++) Vt[vp * 16 + i][vj] = v0[i];
#pragma unroll
    for (int i = 0; i < 8; i++) Vt[vp * 16 + 8 + i][vj] = v1[i];
  }

  // ---- Q fragments direct to registers (A-frag: lane(cl,q) = Q[row=cl][k=q*8]) ----
  const _Float16* qsrc = QKV + (size_t)(b * 64 + m0 + cl) * 1536 + h * 64 + q * 8;
  half8 qa0 = *(const half8*)qsrc;          // k = 0..31 slice
  half8 qa1 = *(const half8*)(qsrc + 32);   // k = 32..63 slice

  __syncthreads();   // K staged (vmcnt drained) + Vt written

  // ---- S = Q K^T ----
  f32x4 s[4] = {};
#pragma unroll
  for (int nt = 0; nt < 4; nt++) {
    half8 b0 = *(const half8*)(Ks + nt * 1024 + lane8);
    half8 b1 = *(const half8*)(Ks + nt * 1024 + 512 + lane8);
    s[nt] = __builtin_amdgcn_mfma_f32_16x16x32_f16(qa0, b0, s[nt], 0, 0, 0);
    s[nt] = __builtin_amdgcn_mfma_f32_16x16x32_f16(qa1, b1, s[nt], 0, 0, 0);
  }

  // ---- softmax over 64 keys per row (row=q*4+r, keys spread over cl x nt) ----
  constexpr float SC = 0.125f * 1.44269504088896340736f;  // scale * log2(e)
#pragma unroll
  for (int r = 0; r < 4; r++) {
    float mx = fmaxf(fmaxf(s[0][r], s[1][r]), fmaxf(s[2][r], s[3][r]));
    mx = fmaxf(mx, __shfl_xor(mx, 1));
    mx = fmaxf(mx, __shfl_xor(mx, 2));
    mx = fmaxf(mx, __shfl_xor(mx, 4));
    mx = fmaxf(mx, __shfl_xor(mx, 8));
    float e[4], ssum = 0.f;
#pragma unroll
    for (int nt = 0; nt < 4; nt++) { e[nt] = exp2f((s[nt][r] - mx) * SC); ssum += e[nt]; }
    ssum += __shfl_xor(ssum, 1);
    ssum += __shfl_xor(ssum, 2);
    ssum += __shfl_xor(ssum, 4);
    ssum += __shfl_xor(ssum, 8);
    float inv = 1.f / ssum;
    const int row = m0 + q * 4 + r;
#pragma unroll
    for (int nt = 0; nt < 4; nt++) Ps[row][nt * 16 + cl] = (_Float16)(e[nt] * inv);
  }
  __syncthreads();

  // ---- O = P V  (a: Ps rows; b: Vt rows = V columns; 72-pad rotates groups) ----
  f32x4 o[4] = {};
#pragma unroll
  for (int ks = 0; ks < 2; ks++) {
    half8 a = *(const half8*)&Ps[m0 + cl][ks * 32 + q * 8];
#pragma unroll
    for (int nt = 0; nt < 4; nt++) {
      half8 bb = *(const half8*)&Vt[nt * 16 + cl][ks * 32 + q * 8];
      o[nt] = __builtin_amdgcn_mfma_f32_16x16x32_f16(a, bb, o[nt], 0, 0, 0);
    }
  }
#pragma unroll
  for (int nt = 0; nt < 4; nt++)
#pragma unroll
    for (int r = 0; r < 4; r++)
      Os[m0 + q * 4 + r][nt * 16 + cl] = (_Float16)o[nt][r];
  __syncthreads();

  // ---- coalesced write-out ----
  {
    const int row = t >> 2, cs = t & 3;
    half8 h0 = *(const half8*)&Os[row][cs * 16];
    half8 h1 = *(const half8*)&Os[row][cs * 16 + 8];
    _Float16* dst = Out + (size_t)(b * 64 + row) * 512 + h * 64 + cs * 16;
    *(half8*)dst = h0;
    *((half8*)dst + 1) = h1;
  }
}

// ---------------------------------------------------------------------------
extern "C" void kernel_launch(void* const* d_in, const int* in_sizes, int n_in,
                              void* d_out, int out_size, void* d_ws, size_t ws_size,
                              hipStream_t stream) {
  const float* x      = (const float*)d_in[0];   // 16*4096*512
  const float* qkv_w  = (const float*)d_in[1];   // 1536*512
  const float* proj_w = (const float*)d_in[2];   // 512*512
  const float* proj_b = (const float*)d_in[3];   // 512
  float* out = (float*)d_out;

  char* ws = (char*)d_ws;
  _Float16* QKVh = (_Float16*)ws;                 // 65536*1536 fp16 = 201,326,592 B
  _Float16* Xh   = (_Float16*)(ws + 201326592);   // 65536*512 fp16 = 67,108,864 B
  _Float16* Outh = Xh;                            // alias: Xh dead after qkv_gemm
  _Float16* Wq   = (_Float16*)(ws + 268435456);   // 1536*512 fp16
  _Float16* Wp   = (_Float16*)(ws + 270008320);   // 512*512 fp16

  cvt_f32_f16<<<16384, 256, 0, stream>>>(x, Xh, 16 * 4096 * 512);
  cvt_f32_f16<<<384, 256, 0, stream>>>(qkv_w, Wq, 1536 * 512);
  cvt_f32_f16<<<128, 256, 0, stream>>>(proj_w, Wp, 512 * 512);
  gemm_wide<1536, 12, false><<<3072, 256, 0, stream>>>(Xh, Wq, nullptr, QKVh);
  attn_win<<<dim3(8, 1024), 256, 0, stream>>>(QKVh, Outh);
  gemm_wide<512, 4, true><<<1024, 256, 0, stream>>>(Outh, Wp, proj_b, out);
}